// Round 6
// baseline (385.317 us; speedup 1.0000x reference)
//
#include <hip/hip_runtime.h>
#include <stdint.h>
#include <math.h>

typedef __bf16 bf16_t;
typedef __bf16 bf16x8 __attribute__((ext_vector_type(8)));
typedef __bf16 bf16x4 __attribute__((ext_vector_type(4)));
typedef float f32x4 __attribute__((ext_vector_type(4)));

#define B_ 4
#define L_ 2048
#define D_ 1024
#define H_ 16
#define DH_ 64
#define M_ (B_ * L_)   // 8192
#define QSCALE 0.18033688011112042f   // 0.125 * log2(e): softmax in exp2 domain

__device__ __forceinline__ void gload16(const bf16_t* gsrc, bf16_t* ldst) {
    __builtin_amdgcn_global_load_lds(
        (__attribute__((address_space(1))) void*)(void*)(gsrc),
        (__attribute__((address_space(3))) void*)(ldst), 16, 0, 0);
}

__device__ __forceinline__ float gelu_exact(float v) {
    return 0.5f * v * (1.0f + erff(v * 0.70710678118654752f));
}

__device__ __forceinline__ float fast_exp2(float x) {
#if __has_builtin(__builtin_amdgcn_exp2f)
    return __builtin_amdgcn_exp2f(x);
#else
    return exp2f(x);
#endif
}

// ---------------- fused prep: 5 weight transposes + maskbias(+flags) + LN1 ----------------
// grid.x = 5120 (transpose) + 32 (maskbias) + 8192 (ln1) = 13344
__global__ __launch_bounds__(256) void prep_kernel(const float* __restrict__ W0, const float* __restrict__ W1,
                                                   const float* __restrict__ W2, const float* __restrict__ W3,
                                                   const float* __restrict__ W4,
                                                   bf16_t* __restrict__ T0, bf16_t* __restrict__ T1,
                                                   bf16_t* __restrict__ T2, bf16_t* __restrict__ T3,
                                                   bf16_t* __restrict__ T4,
                                                   const int* __restrict__ mask,
                                                   float* __restrict__ mb,
                                                   unsigned char* __restrict__ flags,
                                                   const float* __restrict__ x,
                                                   const float* __restrict__ g1,
                                                   const float* __restrict__ b1,
                                                   bf16_t* __restrict__ h) {
    const int z = blockIdx.x;
    const int t = threadIdx.x;
    if (z < 5120) {
        const int wsel = z >> 10, tile = z & 1023;
        const float* W; bf16_t* T;
        switch (wsel) {
            case 0: W = W0; T = T0; break;
            case 1: W = W1; T = T1; break;
            case 2: W = W2; T = T2; break;
            case 3: W = W3; T = T3; break;
            default: W = W4; T = T4; break;
        }
        __shared__ float tl[32][33];
        const int xx = t & 31, y0 = t >> 5;
        const int bx = (tile & 31) * 32, by = (tile >> 5) * 32;
        for (int kk = 0; kk < 4; ++kk)
            tl[y0 + kk * 8][xx] = W[(size_t)(by + y0 + kk * 8) * D_ + bx + xx];
        __syncthreads();
        for (int kk = 0; kk < 4; ++kk)
            T[(size_t)(bx + y0 + kk * 8) * D_ + by + xx] = (bf16_t)tl[xx][y0 + kk * 8];
    } else if (z < 5152) {
        const int blk = z - 5120;
        const int i = blk * 256 + t;
        const int m = mask[i];
        mb[i] = m ? 0.f : -1.0e30f;
        const unsigned long long bal = __ballot(m != 0);
        __shared__ unsigned char ok[4];
        if ((t & 63) == 0) ok[t >> 6] = (bal == ~0ull) ? 1 : 0;
        __syncthreads();
        if (t < 2)
            flags[blk * 2 + t] = (unsigned char)(ok[t * 2] & ok[t * 2 + 1]);
    } else {
        const int row = z - 5152;
        const float4 v = *(const float4*)(x + (size_t)row * D_ + t * 4);
        float s = v.x + v.y + v.z + v.w;
        float s2 = v.x * v.x + v.y * v.y + v.z * v.z + v.w * v.w;
        for (int m = 1; m < 64; m <<= 1) { s += __shfl_xor(s, m, 64); s2 += __shfl_xor(s2, m, 64); }
        __shared__ float red[2][4];
        if ((t & 63) == 0) { red[0][t >> 6] = s; red[1][t >> 6] = s2; }
        __syncthreads();
        s = red[0][0] + red[0][1] + red[0][2] + red[0][3];
        s2 = red[1][0] + red[1][1] + red[1][2] + red[1][3];
        const float mean = s * (1.f / 1024.f);
        const float var = s2 * (1.f / 1024.f) - mean * mean;
        const float rstd = rsqrtf(var + 1e-6f);
        const float4 gv = *(const float4*)(g1 + t * 4);
        const float4 bv = *(const float4*)(b1 + t * 4);
        union { bf16_t h4[4]; uint2 u; } o;
        o.h4[0] = (bf16_t)((v.x - mean) * rstd * gv.x + bv.x);
        o.h4[1] = (bf16_t)((v.y - mean) * rstd * gv.y + bv.y);
        o.h4[2] = (bf16_t)((v.z - mean) * rstd * gv.z + bv.z);
        o.h4[3] = (bf16_t)((v.w - mean) * rstd * gv.w + bv.w);
        *(uint2*)(h + (size_t)row * D_ + t * 4) = o.u;
    }
}

// ---------------- per-head V transpose (key-PERMUTED): vt[b,h,d,pos], pos within 32-chunk ----
// pos = g*8 + b16*4 + r  for actual key = b16*16 + g*4 + r  (matches 16x16x32 B-operand layout)
#define VTR_STRIDE 76
__global__ __launch_bounds__(256) void vtrans_kernel(const bf16_t* __restrict__ vb,
                                                     bf16_t* __restrict__ vt) {
    __shared__ bf16_t tile[128 * VTR_STRIDE];
    const int t = threadIdx.x;
    const int bh = blockIdx.y, b = bh >> 4, h = bh & 15;
    const int k0 = blockIdx.x * 128;
    #pragma unroll
    for (int it = 0; it < 4; ++it) {
        const int row = it * 32 + (t >> 3), c8 = (t & 7) * 8;
        *(uint4*)&tile[row * VTR_STRIDE + c8] =
            *(const uint4*)(vb + (size_t)(b * L_ + k0 + row) * D_ + h * DH_ + c8);
    }
    __syncthreads();
    #pragma unroll
    for (int it = 0; it < 4; ++it) {
        const int d = it * 16 + (t >> 4), pos0 = (t & 15) * 8;
        const int base32 = pos0 & ~31, g = (pos0 >> 3) & 3;
        union { uint4 u; bf16_t e[8]; } tv;
        #pragma unroll
        for (int j = 0; j < 8; ++j) {
            const int kk = base32 + ((j >> 2) << 4) + (g << 2) + (j & 3);
            tv.e[j] = tile[kk * VTR_STRIDE + d];
        }
        *(uint4*)&vt[((size_t)bh * DH_ + d) * L_ + k0 + pos0] = tv.u;
    }
}

// ---------------- residual add (bf16 attn) + LayerNorm 2 -> resid bf16, h bf16 ----------------
__global__ __launch_bounds__(256) void add_ln2_kernel(const float* __restrict__ x,
                                                      const bf16_t* __restrict__ attnb,
                                                      const float* __restrict__ g,
                                                      const float* __restrict__ b,
                                                      bf16_t* __restrict__ residb,
                                                      bf16_t* __restrict__ h) {
    const int row = blockIdx.x, t = threadIdx.x;
    const float4 xv = *(const float4*)(x + (size_t)row * D_ + t * 4);
    union { uint2 u; bf16_t h4[4]; } ai;
    ai.u = *(const uint2*)(attnb + (size_t)row * D_ + t * 4);
    float4 v;
    v.x = xv.x + (float)ai.h4[0]; v.y = xv.y + (float)ai.h4[1];
    v.z = xv.z + (float)ai.h4[2]; v.w = xv.w + (float)ai.h4[3];
    union { bf16_t h4[4]; uint2 u; } rs;
    rs.h4[0] = (bf16_t)v.x; rs.h4[1] = (bf16_t)v.y; rs.h4[2] = (bf16_t)v.z; rs.h4[3] = (bf16_t)v.w;
    *(uint2*)(residb + (size_t)row * D_ + t * 4) = rs.u;
    float s = v.x + v.y + v.z + v.w;
    float s2 = v.x * v.x + v.y * v.y + v.z * v.z + v.w * v.w;
    for (int m = 1; m < 64; m <<= 1) { s += __shfl_xor(s, m, 64); s2 += __shfl_xor(s2, m, 64); }
    __shared__ float red[2][4];
    if ((t & 63) == 0) { red[0][t >> 6] = s; red[1][t >> 6] = s2; }
    __syncthreads();
    s = red[0][0] + red[0][1] + red[0][2] + red[0][3];
    s2 = red[1][0] + red[1][1] + red[1][2] + red[1][3];
    const float mean = s * (1.f / 1024.f);
    const float var = s2 * (1.f / 1024.f) - mean * mean;
    const float rstd = rsqrtf(var + 1e-6f);
    const float4 gv = *(const float4*)(g + t * 4);
    const float4 bv = *(const float4*)(b + t * 4);
    union { bf16_t h4[4]; uint2 u; } o;
    o.h4[0] = (bf16_t)((v.x - mean) * rstd * gv.x + bv.x);
    o.h4[1] = (bf16_t)((v.y - mean) * rstd * gv.y + bv.y);
    o.h4[2] = (bf16_t)((v.z - mean) * rstd * gv.z + bv.z);
    o.h4[3] = (bf16_t)((v.w - mean) * rstd * gv.w + bv.w);
    *(uint2*)(h + (size_t)row * D_ + t * 4) = o.u;
}

// ---------------- fused QKV GEMM; q scaled by 0.125*log2e ----------------
__global__ __launch_bounds__(256) void gemm_qkv(const bf16_t* __restrict__ A,
                                                const bf16_t* __restrict__ BT,
                                                const float* __restrict__ bq,
                                                const float* __restrict__ bk,
                                                const float* __restrict__ bv,
                                                bf16_t* __restrict__ qb,
                                                bf16_t* __restrict__ kb,
                                                bf16_t* __restrict__ vb) {
    constexpr int K = 1024;
    __shared__ bf16_t As[128 * 32];
    __shared__ bf16_t Bs[128 * 32];
    const int t = threadIdx.x;
    const int wave = t >> 6, lane = t & 63;
    const int l16 = lane & 15, g4 = lane >> 4;
    const int bm = blockIdx.x * 128, bn = blockIdx.y * 128;
    const int wm = (wave >> 1) * 64, wn = (wave & 1) * 64;

    f32x4 acc[4][4];
    for (int i = 0; i < 4; ++i)
        for (int j = 0; j < 4; ++j) acc[i][j] = (f32x4){0.f, 0.f, 0.f, 0.f};

    const int ar = t >> 2, ak = (t & 3) * 8;
    const bf16_t* Ag = A + (size_t)(bm + ar) * K + ak;
    const bf16_t* Bg = BT + (size_t)(bn + ar) * K + ak;
    bf16_t* Al = As + t * 8;
    bf16_t* Bl = Bs + t * 8;

    for (int kk = 0; kk < K; kk += 32) {
        __syncthreads();
        gload16(Ag + kk, Al);
        gload16(Ag + (size_t)64 * K + kk, Al + 2048);
        gload16(Bg + kk, Bl);
        gload16(Bg + (size_t)64 * K + kk, Bl + 2048);
        __syncthreads();
        bf16x8 af[4], bfr[4];
        for (int i = 0; i < 4; ++i)
            af[i] = *(const bf16x8*)&As[(wm + i * 16 + l16) * 32 + g4 * 8];
        for (int j = 0; j < 4; ++j)
            bfr[j] = *(const bf16x8*)&Bs[(wn + j * 16 + l16) * 32 + g4 * 8];
        for (int i = 0; i < 4; ++i)
            for (int j = 0; j < 4; ++j)
                acc[i][j] = __builtin_amdgcn_mfma_f32_16x16x32_bf16(af[i], bfr[j], acc[i][j], 0, 0, 0);
    }

    const int which = bn >> 10;             // 0=q, 1=k, 2=v
    const int c0 = bn & 1023;
    const float* bias = (which == 0) ? bq : (which == 1) ? bk : bv;
    bf16_t* ob = (which == 0) ? qb : (which == 1) ? kb : vb;
    const float scale = (which == 0) ? QSCALE : 1.0f;

    for (int i = 0; i < 4; ++i)
        for (int j = 0; j < 4; ++j) {
            const int col = c0 + wn + j * 16 + l16;
            const float bvv = bias[col];
            const int row0 = bm + wm + i * 16 + g4 * 4;
            for (int r = 0; r < 4; ++r) {
                const float vv = (acc[i][j][r] + bvv) * scale;
                ob[(size_t)(row0 + r) * D_ + col] = (bf16_t)vv;
            }
        }
}

// ---------------- GEMM: MODE 1 gelu->bf16, MODE 2 +resid(bf16)->f32 ----------------
template <int MODE>
__global__ __launch_bounds__(256) void gemm_bt(const bf16_t* __restrict__ A,
                                               const bf16_t* __restrict__ BT,
                                               const float* __restrict__ bias,
                                               const bf16_t* __restrict__ residb,
                                               bf16_t* __restrict__ outb,
                                               float* __restrict__ outf) {
    constexpr int K = 1024, N = 1024;
    __shared__ bf16_t As[128 * 32];
    __shared__ bf16_t Bs[128 * 32];
    const int t = threadIdx.x;
    const int wave = t >> 6, lane = t & 63;
    const int l16 = lane & 15, g4 = lane >> 4;
    const int bm = blockIdx.x * 128, bn = blockIdx.y * 128;
    const int wm = (wave >> 1) * 64, wn = (wave & 1) * 64;

    f32x4 acc[4][4];
    for (int i = 0; i < 4; ++i)
        for (int j = 0; j < 4; ++j) acc[i][j] = (f32x4){0.f, 0.f, 0.f, 0.f};

    const int ar = t >> 2, ak = (t & 3) * 8;
    const bf16_t* Ag = A + (size_t)(bm + ar) * K + ak;
    const bf16_t* Bg = BT + (size_t)(bn + ar) * K + ak;
    bf16_t* Al = As + t * 8;
    bf16_t* Bl = Bs + t * 8;

    for (int kk = 0; kk < K; kk += 32) {
        __syncthreads();
        gload16(Ag + kk, Al);
        gload16(Ag + (size_t)64 * K + kk, Al + 2048);
        gload16(Bg + kk, Bl);
        gload16(Bg + (size_t)64 * K + kk, Bl + 2048);
        __syncthreads();
        bf16x8 af[4], bfr[4];
        for (int i = 0; i < 4; ++i)
            af[i] = *(const bf16x8*)&As[(wm + i * 16 + l16) * 32 + g4 * 8];
        for (int j = 0; j < 4; ++j)
            bfr[j] = *(const bf16x8*)&Bs[(wn + j * 16 + l16) * 32 + g4 * 8];
        for (int i = 0; i < 4; ++i)
            for (int j = 0; j < 4; ++j)
                acc[i][j] = __builtin_amdgcn_mfma_f32_16x16x32_bf16(af[i], bfr[j], acc[i][j], 0, 0, 0);
    }

    for (int i = 0; i < 4; ++i)
        for (int j = 0; j < 4; ++j) {
            const int col = bn + wn + j * 16 + l16;
            const float bv = bias[col];
            const int row0 = bm + wm + i * 16 + g4 * 4;
            for (int r = 0; r < 4; ++r) {
                float vv = acc[i][j][r] + bv;
                const size_t idx = (size_t)(row0 + r) * N + col;
                if (MODE == 1) {
                    outb[idx] = (bf16_t)gelu_exact(vv);
                } else {
                    outf[idx] = vv + (float)residb[idx];
                }
            }
        }
}

// ---------------- flash attention v6: 32KB LDS (XOR-swizzled V), 4 blocks/CU ----------------
#define OS_STRIDE 72
__global__ __launch_bounds__(256, 4) void attn_kernel(const bf16_t* __restrict__ q,
                                                      const bf16_t* __restrict__ k,
                                                      const bf16_t* __restrict__ vt,
                                                      const float* __restrict__ maskbias,
                                                      const unsigned char* __restrict__ mflags,
                                                      bf16_t* __restrict__ attnb) {
    __shared__ char smem[32768];
    bf16_t* Ks = (bf16_t*)smem;                  // [128][64], XOR-swizzled 8-elem groups
    bf16_t* VT = (bf16_t*)(smem + 16384);        // [64][128], XOR-swizzled 8-elem groups
    bf16_t* Os = (bf16_t*)smem;                  // epilogue overlay [128][72]

    const int t = threadIdx.x;
    const int wave = t >> 6, lane = t & 63;
    const int l16 = lane & 15, g4 = lane >> 4;
    const int id = blockIdx.x;
    const int xcd = id & 7, seq = id >> 3;
    const int bh = xcd * 8 + (seq >> 4);
    const int b = bh >> 4, h = bh & 15;
    const int q0 = (seq & 15) * 128;

    // Q fragments (B-operand of S^T): lane n=q(l16), holds d = c*32 + g4*8 + j
    bf16x8 qf[2][2];
    for (int ti = 0; ti < 2; ++ti)
        for (int c = 0; c < 2; ++c)
            qf[ti][c] = *(const bf16x8*)(q + (size_t)(b * L_ + q0 + wave * 32 + ti * 16 + l16) * D_ +
                                         h * DH_ + c * 32 + g4 * 8);

    f32x4 accO[2][5];   // [ti][dt]; dt=4 is the ones-row = running row-sum l
    for (int ti = 0; ti < 2; ++ti)
        for (int dt = 0; dt < 5; ++dt) accO[ti][dt] = (f32x4){0.f, 0.f, 0.f, 0.f};

    const bf16_t ozv = (l16 == 0) ? (bf16_t)1.0f : (bf16_t)0.0f;
    const bf16x8 ones8 = (bf16x8){ozv, ozv, ozv, ozv, ozv, ozv, ozv, ozv};

    // K staging (global_load_lds, XOR swizzle on 8-elem groups within each 64-elem row)
    const int krow0 = t >> 3, kcg = t & 7;
    const int klcg = kcg ^ (krow0 & 7);
    const bf16_t* kbase = k + (size_t)(b * L_ + krow0) * D_ + h * DH_ + klcg * 8;
    bf16_t* kdst = Ks + t * 8;
    // V staging: vector loads from pre-transposed vt, XOR swizzle on 16 groups/row
    const int vrow0 = t >> 4, vkg = t & 15;
    const bf16_t* vbase = vt + ((size_t)bh * DH_ + vrow0) * L_ + vkg * 8;
    bf16_t* vdst = &VT[vrow0 * 128 + (vkg ^ (vrow0 & 15)) * 8];

    // read bases (loop-invariant)
    const int kb0 = l16 * 64 + ((g4 ^ (l16 & 7)) * 8);
    const int kb1 = l16 * 64 + (((g4 + 4) ^ (l16 & 7)) * 8);
    int voff[4];
    #pragma unroll
    for (int c = 0; c < 4; ++c) voff[c] = l16 * 128 + (((c << 2) + g4) ^ l16) * 8;
    const unsigned char* flg = mflags + b * 16;

    for (int k0 = 0; k0 < L_; k0 += 128) {
        __syncthreads();
        #pragma unroll
        for (int it = 0; it < 4; ++it)
            gload16(kbase + (size_t)(k0 + it * 32) * D_, kdst + it * 2048);
        #pragma unroll
        for (int it = 0; it < 4; ++it) {
            const uint4 vv = *(const uint4*)(vbase + (size_t)(it * 16) * L_ + k0);
            *(uint4*)(vdst + it * 16 * 128) = vv;
        }
        __syncthreads();

        // S^T = K Q^T (both ti), C-layout: col=l16=q, row=g4*4+r=key
        f32x4 s0[8], s1[8];
        #pragma unroll
        for (int tj = 0; tj < 8; ++tj) {
            const bf16x8 kf0 = *(const bf16x8*)&Ks[tj * 1024 + kb0];
            const bf16x8 kf1 = *(const bf16x8*)&Ks[tj * 1024 + kb1];
            f32x4 a = (f32x4){0.f, 0.f, 0.f, 0.f};
            a = __builtin_amdgcn_mfma_f32_16x16x32_bf16(kf0, qf[0][0], a, 0, 0, 0);
            a = __builtin_amdgcn_mfma_f32_16x16x32_bf16(kf1, qf[0][1], a, 0, 0, 0);
            s0[tj] = a;
            f32x4 a2 = (f32x4){0.f, 0.f, 0.f, 0.f};
            a2 = __builtin_amdgcn_mfma_f32_16x16x32_bf16(kf0, qf[1][0], a2, 0, 0, 0);
            a2 = __builtin_amdgcn_mfma_f32_16x16x32_bf16(kf1, qf[1][1], a2, 0, 0, 0);
            s1[tj] = a2;
        }

        // mask (slow path only when some key in this chunk is masked)
        if (!flg[k0 >> 7]) {
            #pragma unroll
            for (int tj = 0; tj < 8; ++tj) {
                const float4 mb = *(const float4*)&maskbias[b * L_ + k0 + tj * 16 + g4 * 4];
                s0[tj][0] += mb.x; s0[tj][1] += mb.y; s0[tj][2] += mb.z; s0[tj][3] += mb.w;
                s1[tj][0] += mb.x; s1[tj][1] += mb.y; s1[tj][2] += mb.z; s1[tj][3] += mb.w;
            }
        }

        // p = exp2(s); pack per 32-key chunk: pb8 = {s[2c][0..3], s[2c+1][0..3]}
        bf16x8 pb0[4], pb1[4];
        #pragma unroll
        for (int c = 0; c < 4; ++c) {
            pb0[c] = (bf16x8){(bf16_t)fast_exp2(s0[2 * c][0]), (bf16_t)fast_exp2(s0[2 * c][1]),
                              (bf16_t)fast_exp2(s0[2 * c][2]), (bf16_t)fast_exp2(s0[2 * c][3]),
                              (bf16_t)fast_exp2(s0[2 * c + 1][0]), (bf16_t)fast_exp2(s0[2 * c + 1][1]),
                              (bf16_t)fast_exp2(s0[2 * c + 1][2]), (bf16_t)fast_exp2(s0[2 * c + 1][3])};
            pb1[c] = (bf16x8){(bf16_t)fast_exp2(s1[2 * c][0]), (bf16_t)fast_exp2(s1[2 * c][1]),
                              (bf16_t)fast_exp2(s1[2 * c][2]), (bf16_t)fast_exp2(s1[2 * c][3]),
                              (bf16_t)fast_exp2(s1[2 * c + 1][0]), (bf16_t)fast_exp2(s1[2 * c + 1][1]),
                              (bf16_t)fast_exp2(s1[2 * c + 1][2]), (bf16_t)fast_exp2(s1[2 * c + 1][3])};
        }

        // PV: O^T += V^T(A) x P^T(B) via 16x16x32; dt=4 ones-row accumulates l
        #pragma unroll
        for (int c = 0; c < 4; ++c) {
            #pragma unroll
            for (int dt = 0; dt < 4; ++dt) {
                const bf16x8 va = *(const bf16x8*)&VT[voff[c] + dt * 2048];
                accO[0][dt] = __builtin_amdgcn_mfma_f32_16x16x32_bf16(va, pb0[c], accO[0][dt], 0, 0, 0);
                accO[1][dt] = __builtin_amdgcn_mfma_f32_16x16x32_bf16(va, pb1[c], accO[1][dt], 0, 0, 0);
            }
            accO[0][4] = __builtin_amdgcn_mfma_f32_16x16x32_bf16(ones8, pb0[c], accO[0][4], 0, 0, 0);
            accO[1][4] = __builtin_amdgcn_mfma_f32_16x16x32_bf16(ones8, pb1[c], accO[1][4], 0, 0, 0);
        }
    }

    // epilogue: normalize by l, transpose via LDS overlay, bf16 out
    __syncthreads();
    for (int ti = 0; ti < 2; ++ti) {
        const float lv = __shfl(accO[ti][4][0], l16, 64);
        const float rl = 1.0f / lv;
        #pragma unroll
        for (int dt = 0; dt < 4; ++dt) {
            bf16x4 o4 = (bf16x4){(bf16_t)(accO[ti][dt][0] * rl), (bf16_t)(accO[ti][dt][1] * rl),
                                 (bf16_t)(accO[ti][dt][2] * rl), (bf16_t)(accO[ti][dt][3] * rl)};
            *(bf16x4*)&Os[(wave * 32 + ti * 16 + l16) * OS_STRIDE + dt * 16 + g4 * 4] = o4;
        }
    }
    __syncthreads();
    for (int cc = 0; cc < 4; ++cc) {
        const int c2 = t + cc * 256;
        const int row = c2 >> 3, k8 = c2 & 7;
        const uint4 vv = *(const uint4*)&Os[row * OS_STRIDE + k8 * 8];
        *(uint4*)&attnb[(size_t)(b * L_ + q0 + row) * D_ + h * DH_ + k8 * 8] = vv;
    }
}

extern "C" void kernel_launch(void* const* d_in, const int* in_sizes, int n_in,
                              void* d_out, int out_size, void* d_ws, size_t ws_size,
                              hipStream_t stream) {
    const float* x    = (const float*)d_in[0];
    const int*   mask = (const int*)d_in[1];
    const float* Wq   = (const float*)d_in[2];
    const float* bq   = (const float*)d_in[3];
    const float* Wk   = (const float*)d_in[4];
    const float* bk   = (const float*)d_in[5];
    const float* Wv   = (const float*)d_in[6];
    const float* bv   = (const float*)d_in[7];
    const float* g1   = (const float*)d_in[8];
    const float* b1   = (const float*)d_in[9];
    const float* g2   = (const float*)d_in[10];
    const float* b2   = (const float*)d_in[11];
    const float* Wo1  = (const float*)d_in[12];
    const float* bo1  = (const float*)d_in[13];
    const float* Wo2  = (const float*)d_in[14];
    const float* bo2  = (const float*)d_in[15];

    char* ws = (char*)d_ws;
    const size_t MBs = 1ull << 20;
    bf16_t* WqkvT = (bf16_t*)(ws + 0 * MBs);          // [3072][1024] bf16
    bf16_t* Wo1T  = (bf16_t*)(ws + 6 * MBs);
    bf16_t* Wo2T  = (bf16_t*)(ws + 8 * MBs);
    bf16_t* h1    = (bf16_t*)(ws + 10 * MBs);         // dead after gemm_qkv
    bf16_t* vtb   = h1;                               // vt overlays h1 (16 MB)
    bf16_t* qb    = (bf16_t*)(ws + 26 * MBs);
    bf16_t* kb    = (bf16_t*)(ws + 42 * MBs);
    bf16_t* vb    = (bf16_t*)(ws + 58 * MBs);
    bf16_t* attnb = (bf16_t*)(ws + 74 * MBs);
    bf16_t* residb= (bf16_t*)(ws + 90 * MBs);
    float*  mbias = (float*)(ws + 106 * MBs);
    unsigned char* mflags = (unsigned char*)(ws + 107 * MBs);
    bf16_t* h2    = qb;   // reuse
    bf16_t* gact  = kb;   // reuse

    prep_kernel<<<dim3(5120 + 32 + 8192), 256, 0, stream>>>(
        Wq, Wk, Wv, Wo1, Wo2,
        WqkvT, WqkvT + (size_t)D_ * D_, WqkvT + (size_t)2 * D_ * D_, Wo1T, Wo2T,
        mask, mbias, mflags, x, g1, b1, h1);

    gemm_qkv<<<dim3(M_ / 128, 3 * D_ / 128), 256, 0, stream>>>(h1, WqkvT, bq, bk, bv, qb, kb, vb);

    vtrans_kernel<<<dim3(L_ / 128, B_ * H_), 256, 0, stream>>>(vb, vtb);

    attn_kernel<<<dim3(1024), 256, 0, stream>>>(qb, kb, vtb, mbias, mflags, attnb);

    add_ln2_kernel<<<M_, 256, 0, stream>>>(x, attnb, g2, b2, residb, h2);

    const dim3 gg(M_ / 128, D_ / 128);
    gemm_bt<1><<<gg, 256, 0, stream>>>(h2, Wo1T, bo1, nullptr, gact, nullptr);
    gemm_bt<2><<<gg, 256, 0, stream>>>(gact, Wo2T, bo2, residb, nullptr, (float*)d_out);
}

// Round 7
// 335.135 us; speedup vs baseline: 1.1497x; 1.1497x over previous
//
#include <hip/hip_runtime.h>
#include <stdint.h>
#include <math.h>

typedef __bf16 bf16_t;
typedef __bf16 bf16x8 __attribute__((ext_vector_type(8)));
typedef __bf16 bf16x4 __attribute__((ext_vector_type(4)));
typedef float f32x4 __attribute__((ext_vector_type(4)));

#define B_ 4
#define L_ 2048
#define D_ 1024
#define H_ 16
#define DH_ 64
#define M_ (B_ * L_)   // 8192
#define QSCALE 0.18033688011112042f   // 0.125 * log2(e): softmax in exp2 domain

__device__ __forceinline__ void gload16(const bf16_t* gsrc, bf16_t* ldst) {
    __builtin_amdgcn_global_load_lds(
        (__attribute__((address_space(1))) void*)(void*)(gsrc),
        (__attribute__((address_space(3))) void*)(ldst), 16, 0, 0);
}

__device__ __forceinline__ float gelu_exact(float v) {
    return 0.5f * v * (1.0f + erff(v * 0.70710678118654752f));
}

__device__ __forceinline__ float fast_exp2(float x) {
#if __has_builtin(__builtin_amdgcn_exp2f)
    return __builtin_amdgcn_exp2f(x);
#else
    return exp2f(x);
#endif
}

// ---------------- fused prep: 5 weight transposes + maskbias(+flags) + LN1 ----------------
__global__ __launch_bounds__(256) void prep_kernel(const float* __restrict__ W0, const float* __restrict__ W1,
                                                   const float* __restrict__ W2, const float* __restrict__ W3,
                                                   const float* __restrict__ W4,
                                                   bf16_t* __restrict__ T0, bf16_t* __restrict__ T1,
                                                   bf16_t* __restrict__ T2, bf16_t* __restrict__ T3,
                                                   bf16_t* __restrict__ T4,
                                                   const int* __restrict__ mask,
                                                   float* __restrict__ mb,
                                                   unsigned char* __restrict__ flags,
                                                   const float* __restrict__ x,
                                                   const float* __restrict__ g1,
                                                   const float* __restrict__ b1,
                                                   bf16_t* __restrict__ h) {
    const int z = blockIdx.x;
    const int t = threadIdx.x;
    if (z < 5120) {
        const int wsel = z >> 10, tile = z & 1023;
        const float* W; bf16_t* T;
        switch (wsel) {
            case 0: W = W0; T = T0; break;
            case 1: W = W1; T = T1; break;
            case 2: W = W2; T = T2; break;
            case 3: W = W3; T = T3; break;
            default: W = W4; T = T4; break;
        }
        __shared__ float tl[32][33];
        const int xx = t & 31, y0 = t >> 5;
        const int bx = (tile & 31) * 32, by = (tile >> 5) * 32;
        for (int kk = 0; kk < 4; ++kk)
            tl[y0 + kk * 8][xx] = W[(size_t)(by + y0 + kk * 8) * D_ + bx + xx];
        __syncthreads();
        for (int kk = 0; kk < 4; ++kk)
            T[(size_t)(bx + y0 + kk * 8) * D_ + by + xx] = (bf16_t)tl[xx][y0 + kk * 8];
    } else if (z < 5152) {
        const int blk = z - 5120;
        const int i = blk * 256 + t;
        const int m = mask[i];
        mb[i] = m ? 0.f : -1.0e30f;
        const unsigned long long bal = __ballot(m != 0);
        __shared__ unsigned char ok[4];
        if ((t & 63) == 0) ok[t >> 6] = (bal == ~0ull) ? 1 : 0;
        __syncthreads();
        if (t < 2)
            flags[blk * 2 + t] = (unsigned char)(ok[t * 2] & ok[t * 2 + 1]);
    } else {
        const int row = z - 5152;
        const float4 v = *(const float4*)(x + (size_t)row * D_ + t * 4);
        float s = v.x + v.y + v.z + v.w;
        float s2 = v.x * v.x + v.y * v.y + v.z * v.z + v.w * v.w;
        for (int m = 1; m < 64; m <<= 1) { s += __shfl_xor(s, m, 64); s2 += __shfl_xor(s2, m, 64); }
        __shared__ float red[2][4];
        if ((t & 63) == 0) { red[0][t >> 6] = s; red[1][t >> 6] = s2; }
        __syncthreads();
        s = red[0][0] + red[0][1] + red[0][2] + red[0][3];
        s2 = red[1][0] + red[1][1] + red[1][2] + red[1][3];
        const float mean = s * (1.f / 1024.f);
        const float var = s2 * (1.f / 1024.f) - mean * mean;
        const float rstd = rsqrtf(var + 1e-6f);
        const float4 gv = *(const float4*)(g1 + t * 4);
        const float4 bv = *(const float4*)(b1 + t * 4);
        union { bf16_t h4[4]; uint2 u; } o;
        o.h4[0] = (bf16_t)((v.x - mean) * rstd * gv.x + bv.x);
        o.h4[1] = (bf16_t)((v.y - mean) * rstd * gv.y + bv.y);
        o.h4[2] = (bf16_t)((v.z - mean) * rstd * gv.z + bv.z);
        o.h4[3] = (bf16_t)((v.w - mean) * rstd * gv.w + bv.w);
        *(uint2*)(h + (size_t)row * D_ + t * 4) = o.u;
    }
}

// ---------------- per-head V transpose (key-PERMUTED): vt[b,h,d,pos], pos within 32-chunk ----
// pos = g*8 + b16*4 + r  for actual key = b16*16 + g*4 + r  (matches 16x16x32 B-operand layout)
#define VTR_STRIDE 76
__global__ __launch_bounds__(256) void vtrans_kernel(const bf16_t* __restrict__ vb,
                                                     bf16_t* __restrict__ vt) {
    __shared__ bf16_t tile[128 * VTR_STRIDE];
    const int t = threadIdx.x;
    const int bh = blockIdx.y, b = bh >> 4, h = bh & 15;
    const int k0 = blockIdx.x * 128;
    #pragma unroll
    for (int it = 0; it < 4; ++it) {
        const int row = it * 32 + (t >> 3), c8 = (t & 7) * 8;
        *(uint4*)&tile[row * VTR_STRIDE + c8] =
            *(const uint4*)(vb + (size_t)(b * L_ + k0 + row) * D_ + h * DH_ + c8);
    }
    __syncthreads();
    #pragma unroll
    for (int it = 0; it < 4; ++it) {
        const int d = it * 16 + (t >> 4), pos0 = (t & 15) * 8;
        const int base32 = pos0 & ~31, g = (pos0 >> 3) & 3;
        union { uint4 u; bf16_t e[8]; } tv;
        #pragma unroll
        for (int j = 0; j < 8; ++j) {
            const int kk = base32 + ((j >> 2) << 4) + (g << 2) + (j & 3);
            tv.e[j] = tile[kk * VTR_STRIDE + d];
        }
        *(uint4*)&vt[((size_t)bh * DH_ + d) * L_ + k0 + pos0] = tv.u;
    }
}

// ---------------- residual add (bf16 attn) + LayerNorm 2 -> resid bf16, h bf16 ----------------
__global__ __launch_bounds__(256) void add_ln2_kernel(const float* __restrict__ x,
                                                      const bf16_t* __restrict__ attnb,
                                                      const float* __restrict__ g,
                                                      const float* __restrict__ b,
                                                      bf16_t* __restrict__ residb,
                                                      bf16_t* __restrict__ h) {
    const int row = blockIdx.x, t = threadIdx.x;
    const float4 xv = *(const float4*)(x + (size_t)row * D_ + t * 4);
    union { uint2 u; bf16_t h4[4]; } ai;
    ai.u = *(const uint2*)(attnb + (size_t)row * D_ + t * 4);
    float4 v;
    v.x = xv.x + (float)ai.h4[0]; v.y = xv.y + (float)ai.h4[1];
    v.z = xv.z + (float)ai.h4[2]; v.w = xv.w + (float)ai.h4[3];
    union { bf16_t h4[4]; uint2 u; } rs;
    rs.h4[0] = (bf16_t)v.x; rs.h4[1] = (bf16_t)v.y; rs.h4[2] = (bf16_t)v.z; rs.h4[3] = (bf16_t)v.w;
    *(uint2*)(residb + (size_t)row * D_ + t * 4) = rs.u;
    float s = v.x + v.y + v.z + v.w;
    float s2 = v.x * v.x + v.y * v.y + v.z * v.z + v.w * v.w;
    for (int m = 1; m < 64; m <<= 1) { s += __shfl_xor(s, m, 64); s2 += __shfl_xor(s2, m, 64); }
    __shared__ float red[2][4];
    if ((t & 63) == 0) { red[0][t >> 6] = s; red[1][t >> 6] = s2; }
    __syncthreads();
    s = red[0][0] + red[0][1] + red[0][2] + red[0][3];
    s2 = red[1][0] + red[1][1] + red[1][2] + red[1][3];
    const float mean = s * (1.f / 1024.f);
    const float var = s2 * (1.f / 1024.f) - mean * mean;
    const float rstd = rsqrtf(var + 1e-6f);
    const float4 gv = *(const float4*)(g + t * 4);
    const float4 bv = *(const float4*)(b + t * 4);
    union { bf16_t h4[4]; uint2 u; } o;
    o.h4[0] = (bf16_t)((v.x - mean) * rstd * gv.x + bv.x);
    o.h4[1] = (bf16_t)((v.y - mean) * rstd * gv.y + bv.y);
    o.h4[2] = (bf16_t)((v.z - mean) * rstd * gv.z + bv.z);
    o.h4[3] = (bf16_t)((v.w - mean) * rstd * gv.w + bv.w);
    *(uint2*)(h + (size_t)row * D_ + t * 4) = o.u;
}

// ---------------- fused QKV GEMM; q scaled by 0.125*log2e ----------------
__global__ __launch_bounds__(256) void gemm_qkv(const bf16_t* __restrict__ A,
                                                const bf16_t* __restrict__ BT,
                                                const float* __restrict__ bq,
                                                const float* __restrict__ bk,
                                                const float* __restrict__ bv,
                                                bf16_t* __restrict__ qb,
                                                bf16_t* __restrict__ kb,
                                                bf16_t* __restrict__ vb) {
    constexpr int K = 1024;
    __shared__ bf16_t As[128 * 32];
    __shared__ bf16_t Bs[128 * 32];
    const int t = threadIdx.x;
    const int wave = t >> 6, lane = t & 63;
    const int l16 = lane & 15, g4 = lane >> 4;
    const int bm = blockIdx.x * 128, bn = blockIdx.y * 128;
    const int wm = (wave >> 1) * 64, wn = (wave & 1) * 64;

    f32x4 acc[4][4];
    for (int i = 0; i < 4; ++i)
        for (int j = 0; j < 4; ++j) acc[i][j] = (f32x4){0.f, 0.f, 0.f, 0.f};

    const int ar = t >> 2, ak = (t & 3) * 8;
    const bf16_t* Ag = A + (size_t)(bm + ar) * K + ak;
    const bf16_t* Bg = BT + (size_t)(bn + ar) * K + ak;
    bf16_t* Al = As + t * 8;
    bf16_t* Bl = Bs + t * 8;

    for (int kk = 0; kk < K; kk += 32) {
        __syncthreads();
        gload16(Ag + kk, Al);
        gload16(Ag + (size_t)64 * K + kk, Al + 2048);
        gload16(Bg + kk, Bl);
        gload16(Bg + (size_t)64 * K + kk, Bl + 2048);
        __syncthreads();
        bf16x8 af[4], bfr[4];
        for (int i = 0; i < 4; ++i)
            af[i] = *(const bf16x8*)&As[(wm + i * 16 + l16) * 32 + g4 * 8];
        for (int j = 0; j < 4; ++j)
            bfr[j] = *(const bf16x8*)&Bs[(wn + j * 16 + l16) * 32 + g4 * 8];
        for (int i = 0; i < 4; ++i)
            for (int j = 0; j < 4; ++j)
                acc[i][j] = __builtin_amdgcn_mfma_f32_16x16x32_bf16(af[i], bfr[j], acc[i][j], 0, 0, 0);
    }

    const int which = bn >> 10;             // 0=q, 1=k, 2=v
    const int c0 = bn & 1023;
    const float* bias = (which == 0) ? bq : (which == 1) ? bk : bv;
    bf16_t* ob = (which == 0) ? qb : (which == 1) ? kb : vb;
    const float scale = (which == 0) ? QSCALE : 1.0f;

    for (int i = 0; i < 4; ++i)
        for (int j = 0; j < 4; ++j) {
            const int col = c0 + wn + j * 16 + l16;
            const float bvv = bias[col];
            const int row0 = bm + wm + i * 16 + g4 * 4;
            for (int r = 0; r < 4; ++r) {
                const float vv = (acc[i][j][r] + bvv) * scale;
                ob[(size_t)(row0 + r) * D_ + col] = (bf16_t)vv;
            }
        }
}

// ---------------- GEMM: MODE 1 gelu->bf16, MODE 2 +resid(bf16)->f32 ----------------
template <int MODE>
__global__ __launch_bounds__(256) void gemm_bt(const bf16_t* __restrict__ A,
                                               const bf16_t* __restrict__ BT,
                                               const float* __restrict__ bias,
                                               const bf16_t* __restrict__ residb,
                                               bf16_t* __restrict__ outb,
                                               float* __restrict__ outf) {
    constexpr int K = 1024, N = 1024;
    __shared__ bf16_t As[128 * 32];
    __shared__ bf16_t Bs[128 * 32];
    const int t = threadIdx.x;
    const int wave = t >> 6, lane = t & 63;
    const int l16 = lane & 15, g4 = lane >> 4;
    const int bm = blockIdx.x * 128, bn = blockIdx.y * 128;
    const int wm = (wave >> 1) * 64, wn = (wave & 1) * 64;

    f32x4 acc[4][4];
    for (int i = 0; i < 4; ++i)
        for (int j = 0; j < 4; ++j) acc[i][j] = (f32x4){0.f, 0.f, 0.f, 0.f};

    const int ar = t >> 2, ak = (t & 3) * 8;
    const bf16_t* Ag = A + (size_t)(bm + ar) * K + ak;
    const bf16_t* Bg = BT + (size_t)(bn + ar) * K + ak;
    bf16_t* Al = As + t * 8;
    bf16_t* Bl = Bs + t * 8;

    for (int kk = 0; kk < K; kk += 32) {
        __syncthreads();
        gload16(Ag + kk, Al);
        gload16(Ag + (size_t)64 * K + kk, Al + 2048);
        gload16(Bg + kk, Bl);
        gload16(Bg + (size_t)64 * K + kk, Bl + 2048);
        __syncthreads();
        bf16x8 af[4], bfr[4];
        for (int i = 0; i < 4; ++i)
            af[i] = *(const bf16x8*)&As[(wm + i * 16 + l16) * 32 + g4 * 8];
        for (int j = 0; j < 4; ++j)
            bfr[j] = *(const bf16x8*)&Bs[(wn + j * 16 + l16) * 32 + g4 * 8];
        for (int i = 0; i < 4; ++i)
            for (int j = 0; j < 4; ++j)
                acc[i][j] = __builtin_amdgcn_mfma_f32_16x16x32_bf16(af[i], bfr[j], acc[i][j], 0, 0, 0);
    }

    for (int i = 0; i < 4; ++i)
        for (int j = 0; j < 4; ++j) {
            const int col = bn + wn + j * 16 + l16;
            const float bv = bias[col];
            const int row0 = bm + wm + i * 16 + g4 * 4;
            for (int r = 0; r < 4; ++r) {
                float vv = acc[i][j][r] + bv;
                const size_t idx = (size_t)(row0 + r) * N + col;
                if (MODE == 1) {
                    outb[idx] = (bf16_t)gelu_exact(vv);
                } else {
                    outf[idx] = vv + (float)residb[idx];
                }
            }
        }
}

// ---------------- flash attention v7: 32KB swizzled LDS, launch_bounds(256,3) (no spill) ----
#define OS_STRIDE 72
__global__ __launch_bounds__(256, 3) void attn_kernel(const bf16_t* __restrict__ q,
                                                      const bf16_t* __restrict__ k,
                                                      const bf16_t* __restrict__ vt,
                                                      const float* __restrict__ maskbias,
                                                      const unsigned char* __restrict__ mflags,
                                                      bf16_t* __restrict__ attnb) {
    __shared__ char smem[32768];
    bf16_t* Ks = (bf16_t*)smem;                  // [128][64], XOR-swizzled 8-elem groups
    bf16_t* VT = (bf16_t*)(smem + 16384);        // [64][128], XOR-swizzled 8-elem groups
    bf16_t* Os = (bf16_t*)smem;                  // epilogue overlay [128][72]

    const int t = threadIdx.x;
    const int wave = t >> 6, lane = t & 63;
    const int l16 = lane & 15, g4 = lane >> 4;
    const int id = blockIdx.x;
    const int xcd = id & 7, seq = id >> 3;
    const int bh = xcd * 8 + (seq >> 4);
    const int b = bh >> 4, h = bh & 15;
    const int q0 = (seq & 15) * 128;

    // Q fragments (B-operand of S^T): lane n=q(l16), holds d = c*32 + g4*8 + j
    bf16x8 qf[2][2];
    for (int ti = 0; ti < 2; ++ti)
        for (int c = 0; c < 2; ++c)
            qf[ti][c] = *(const bf16x8*)(q + (size_t)(b * L_ + q0 + wave * 32 + ti * 16 + l16) * D_ +
                                         h * DH_ + c * 32 + g4 * 8);

    f32x4 accO[2][5];   // [ti][dt]; dt=4 is the ones-row = running row-sum l
    for (int ti = 0; ti < 2; ++ti)
        for (int dt = 0; dt < 5; ++dt) accO[ti][dt] = (f32x4){0.f, 0.f, 0.f, 0.f};

    const bf16_t ozv = (l16 == 0) ? (bf16_t)1.0f : (bf16_t)0.0f;
    const bf16x8 ones8 = (bf16x8){ozv, ozv, ozv, ozv, ozv, ozv, ozv, ozv};

    // K staging (global_load_lds, XOR swizzle on 8-elem groups within each 64-elem row)
    const int krow0 = t >> 3, kcg = t & 7;
    const int klcg = kcg ^ (krow0 & 7);
    const bf16_t* kbase = k + (size_t)(b * L_ + krow0) * D_ + h * DH_ + klcg * 8;
    bf16_t* kdst = Ks + t * 8;
    // V staging: vector loads from pre-transposed vt, XOR swizzle on 16 groups/row
    const int vrow0 = t >> 4, vkg = t & 15;
    const bf16_t* vbase = vt + ((size_t)bh * DH_ + vrow0) * L_ + vkg * 8;
    bf16_t* vdst = &VT[vrow0 * 128 + (vkg ^ (vrow0 & 15)) * 8];

    // read bases (loop-invariant)
    const int kb0 = l16 * 64 + ((g4 ^ (l16 & 7)) * 8);
    const int kb1 = l16 * 64 + (((g4 + 4) ^ (l16 & 7)) * 8);
    int voff[4];
    #pragma unroll
    for (int c = 0; c < 4; ++c) voff[c] = l16 * 128 + (((c << 2) + g4) ^ l16) * 8;
    const unsigned char* flg = mflags + b * 16;

    for (int k0 = 0; k0 < L_; k0 += 128) {
        __syncthreads();
        #pragma unroll
        for (int it = 0; it < 4; ++it)
            gload16(kbase + (size_t)(k0 + it * 32) * D_, kdst + it * 2048);
        #pragma unroll
        for (int it = 0; it < 4; ++it) {
            const uint4 vv = *(const uint4*)(vbase + (size_t)(it * 16) * L_ + k0);
            *(uint4*)(vdst + it * 16 * 128) = vv;
        }
        __syncthreads();

        // S^T = K Q^T (both ti), C-layout: col=l16=q, row=g4*4+r=key
        f32x4 s0[8], s1[8];
        #pragma unroll
        for (int tj = 0; tj < 8; ++tj) {
            const bf16x8 kf0 = *(const bf16x8*)&Ks[tj * 1024 + kb0];
            const bf16x8 kf1 = *(const bf16x8*)&Ks[tj * 1024 + kb1];
            f32x4 a = (f32x4){0.f, 0.f, 0.f, 0.f};
            a = __builtin_amdgcn_mfma_f32_16x16x32_bf16(kf0, qf[0][0], a, 0, 0, 0);
            a = __builtin_amdgcn_mfma_f32_16x16x32_bf16(kf1, qf[0][1], a, 0, 0, 0);
            s0[tj] = a;
            f32x4 a2 = (f32x4){0.f, 0.f, 0.f, 0.f};
            a2 = __builtin_amdgcn_mfma_f32_16x16x32_bf16(kf0, qf[1][0], a2, 0, 0, 0);
            a2 = __builtin_amdgcn_mfma_f32_16x16x32_bf16(kf1, qf[1][1], a2, 0, 0, 0);
            s1[tj] = a2;
        }

        // mask (slow path only when some key in this chunk is masked)
        if (!flg[k0 >> 7]) {
            #pragma unroll
            for (int tj = 0; tj < 8; ++tj) {
                const float4 mb = *(const float4*)&maskbias[b * L_ + k0 + tj * 16 + g4 * 4];
                s0[tj][0] += mb.x; s0[tj][1] += mb.y; s0[tj][2] += mb.z; s0[tj][3] += mb.w;
                s1[tj][0] += mb.x; s1[tj][1] += mb.y; s1[tj][2] += mb.z; s1[tj][3] += mb.w;
            }
        }

        // p = exp2(s); pack per 32-key chunk: pb8 = {s[2c][0..3], s[2c+1][0..3]}
        bf16x8 pb0[4], pb1[4];
        #pragma unroll
        for (int c = 0; c < 4; ++c) {
            pb0[c] = (bf16x8){(bf16_t)fast_exp2(s0[2 * c][0]), (bf16_t)fast_exp2(s0[2 * c][1]),
                              (bf16_t)fast_exp2(s0[2 * c][2]), (bf16_t)fast_exp2(s0[2 * c][3]),
                              (bf16_t)fast_exp2(s0[2 * c + 1][0]), (bf16_t)fast_exp2(s0[2 * c + 1][1]),
                              (bf16_t)fast_exp2(s0[2 * c + 1][2]), (bf16_t)fast_exp2(s0[2 * c + 1][3])};
            pb1[c] = (bf16x8){(bf16_t)fast_exp2(s1[2 * c][0]), (bf16_t)fast_exp2(s1[2 * c][1]),
                              (bf16_t)fast_exp2(s1[2 * c][2]), (bf16_t)fast_exp2(s1[2 * c][3]),
                              (bf16_t)fast_exp2(s1[2 * c + 1][0]), (bf16_t)fast_exp2(s1[2 * c + 1][1]),
                              (bf16_t)fast_exp2(s1[2 * c + 1][2]), (bf16_t)fast_exp2(s1[2 * c + 1][3])};
        }

        // PV: O^T += V^T(A) x P^T(B) via 16x16x32; dt=4 ones-row accumulates l
        #pragma unroll
        for (int c = 0; c < 4; ++c) {
            #pragma unroll
            for (int dt = 0; dt < 4; ++dt) {
                const bf16x8 va = *(const bf16x8*)&VT[voff[c] + dt * 2048];
                accO[0][dt] = __builtin_amdgcn_mfma_f32_16x16x32_bf16(va, pb0[c], accO[0][dt], 0, 0, 0);
                accO[1][dt] = __builtin_amdgcn_mfma_f32_16x16x32_bf16(va, pb1[c], accO[1][dt], 0, 0, 0);
            }
            accO[0][4] = __builtin_amdgcn_mfma_f32_16x16x32_bf16(ones8, pb0[c], accO[0][4], 0, 0, 0);
            accO[1][4] = __builtin_amdgcn_mfma_f32_16x16x32_bf16(ones8, pb1[c], accO[1][4], 0, 0, 0);
        }
    }

    // epilogue: normalize by l, transpose via LDS overlay, bf16 out
    __syncthreads();
    for (int ti = 0; ti < 2; ++ti) {
        const float lv = __shfl(accO[ti][4][0], l16, 64);
        const float rl = 1.0f / lv;
        #pragma unroll
        for (int dt = 0; dt < 4; ++dt) {
            bf16x4 o4 = (bf16x4){(bf16_t)(accO[ti][dt][0] * rl), (bf16_t)(accO[ti][dt][1] * rl),
                                 (bf16_t)(accO[ti][dt][2] * rl), (bf16_t)(accO[ti][dt][3] * rl)};
            *(bf16x4*)&Os[(wave * 32 + ti * 16 + l16) * OS_STRIDE + dt * 16 + g4 * 4] = o4;
        }
    }
    __syncthreads();
    for (int cc = 0; cc < 4; ++cc) {
        const int c2 = t + cc * 256;
        const int row = c2 >> 3, k8 = c2 & 7;
        const uint4 vv = *(const uint4*)&Os[row * OS_STRIDE + k8 * 8];
        *(uint4*)&attnb[(size_t)(b * L_ + q0 + row) * D_ + h * DH_ + k8 * 8] = vv;
    }
}

extern "C" void kernel_launch(void* const* d_in, const int* in_sizes, int n_in,
                              void* d_out, int out_size, void* d_ws, size_t ws_size,
                              hipStream_t stream) {
    const float* x    = (const float*)d_in[0];
    const int*   mask = (const int*)d_in[1];
    const float* Wq   = (const float*)d_in[2];
    const float* bq   = (const float*)d_in[3];
    const float* Wk   = (const float*)d_in[4];
    const float* bk   = (const float*)d_in[5];
    const float* Wv   = (const float*)d_in[6];
    const float* bv   = (const float*)d_in[7];
    const float* g1   = (const float*)d_in[8];
    const float* b1   = (const float*)d_in[9];
    const float* g2   = (const float*)d_in[10];
    const float* b2   = (const float*)d_in[11];
    const float* Wo1  = (const float*)d_in[12];
    const float* bo1  = (const float*)d_in[13];
    const float* Wo2  = (const float*)d_in[14];
    const float* bo2  = (const float*)d_in[15];

    char* ws = (char*)d_ws;
    const size_t MBs = 1ull << 20;
    bf16_t* WqkvT = (bf16_t*)(ws + 0 * MBs);          // [3072][1024] bf16
    bf16_t* Wo1T  = (bf16_t*)(ws + 6 * MBs);
    bf16_t* Wo2T  = (bf16_t*)(ws + 8 * MBs);
    bf16_t* h1    = (bf16_t*)(ws + 10 * MBs);         // dead after gemm_qkv
    bf16_t* vtb   = h1;                               // vt overlays h1 (16 MB)
    bf16_t* qb    = (bf16_t*)(ws + 26 * MBs);
    bf16_t* kb    = (bf16_t*)(ws + 42 * MBs);
    bf16_t* vb    = (bf16_t*)(ws + 58 * MBs);
    bf16_t* attnb = (bf16_t*)(ws + 74 * MBs);
    bf16_t* residb= (bf16_t*)(ws + 90 * MBs);
    float*  mbias = (float*)(ws + 106 * MBs);
    unsigned char* mflags = (unsigned char*)(ws + 107 * MBs);
    bf16_t* h2    = qb;   // reuse
    bf16_t* gact  = kb;   // reuse

    prep_kernel<<<dim3(5120 + 32 + 8192), 256, 0, stream>>>(
        Wq, Wk, Wv, Wo1, Wo2,
        WqkvT, WqkvT + (size_t)D_ * D_, WqkvT + (size_t)2 * D_ * D_, Wo1T, Wo2T,
        mask, mbias, mflags, x, g1, b1, h1);

    gemm_qkv<<<dim3(M_ / 128, 3 * D_ / 128), 256, 0, stream>>>(h1, WqkvT, bq, bk, bv, qb, kb, vb);

    vtrans_kernel<<<dim3(L_ / 128, B_ * H_), 256, 0, stream>>>(vb, vtb);

    attn_kernel<<<dim3(1024), 256, 0, stream>>>(qb, kb, vtb, mbias, mflags, attnb);

    add_ln2_kernel<<<M_, 256, 0, stream>>>(x, attnb, g2, b2, residb, h2);

    const dim3 gg(M_ / 128, D_ / 128);
    gemm_bt<1><<<gg, 256, 0, stream>>>(h2, Wo1T, bo1, nullptr, gact, nullptr);
    gemm_bt<2><<<gg, 256, 0, stream>>>(gact, Wo2T, bo2, residb, nullptr, (float*)d_out);
}